// Round 14
// baseline (791.205 us; speedup 1.0000x reference)
//
#include <hip/hip_runtime.h>
#include <hip/hip_bf16.h>
#include <hip/hip_fp8.h>
#include <math.h>

#define Nn 20000
#define Ee 320000
#define Dd 512
#define Hh 4
#define Cc 256
#define Ll 4
#define Bb 16
#define HC 1024               // H*C
#define ETOT (Ee + Nn)        // edges + self loops = 340000
#define NEG_SLOPE 0.2f
#define LN_EPS 1e-5f
#define NBLK ((Nn + 255) / 256)   // 79 scan blocks

typedef __attribute__((ext_vector_type(8))) __bf16 bf16x8;
typedef __attribute__((ext_vector_type(4))) __bf16 bf16x4;
typedef __attribute__((ext_vector_type(4))) float f32x4;
typedef __attribute__((ext_vector_type(2))) float f32x2;

// fp8 e4m3 (OCP) x4 decode — HW packed cvt if available
__device__ __forceinline__ f32x4 fp8x4_to_f32(unsigned int v) {
#if __has_builtin(__builtin_amdgcn_cvt_pk_f32_fp8)
    f32x2 lo = __builtin_amdgcn_cvt_pk_f32_fp8((int)v, false);
    f32x2 hi = __builtin_amdgcn_cvt_pk_f32_fp8((int)v, true);
    f32x4 r; r[0] = lo[0]; r[1] = lo[1]; r[2] = hi[0]; r[3] = hi[1];
    return r;
#else
    f32x4 r;
    #pragma unroll
    for (int i = 0; i < 4; ++i) {
        __hip_fp8_e4m3 q; q.__x = (v >> (8 * i)) & 0xff;
        r[i] = (float)q;
    }
    return r;
#endif
}

__device__ __forceinline__ unsigned char f32_to_fp8(float f) {
    return __hip_fp8_e4m3(f).__x;
}

// ---------------- CSR build ----------------

__device__ __forceinline__ void decode_edge(const int* ei, int e, int& s, int& d) {
    if (e < Ee) { s = ei[e]; d = ei[Ee + e]; }
    else        { s = e - Ee; d = e - Ee; }   // self loop
}

__global__ void count_deg_kernel(const int* __restrict__ ei, int* __restrict__ deg) {
    int e = blockIdx.x * blockDim.x + threadIdx.x;
    if (e >= ETOT) return;
    int s, d; decode_edge(ei, e, s, d);
    atomicAdd(&deg[d], 1);
}

__global__ void scan1_kernel(const int* __restrict__ deg, int* __restrict__ tmp,
                             int* __restrict__ bsum) {
    __shared__ int sd[256];
    int tid = threadIdx.x;
    int i = blockIdx.x * 256 + tid;
    sd[tid] = (i < Nn) ? deg[i] : 0;
    __syncthreads();
    for (int off = 1; off < 256; off <<= 1) {
        int t = (tid >= off) ? sd[tid - off] : 0;
        __syncthreads();
        sd[tid] += t;
        __syncthreads();
    }
    if (i < Nn) tmp[i] = sd[tid];
    if (tid == 255) bsum[blockIdx.x] = sd[255];
}

__global__ void scan2_kernel(int* __restrict__ bsum) {   // single block, NBLK<=256
    __shared__ int sd[256];
    int tid = threadIdx.x;
    sd[tid] = (tid < NBLK) ? bsum[tid] : 0;
    __syncthreads();
    for (int off = 1; off < 256; off <<= 1) {
        int t = (tid >= off) ? sd[tid - off] : 0;
        __syncthreads();
        sd[tid] += t;
        __syncthreads();
    }
    if (tid < NBLK) bsum[tid] = sd[tid];
}

__global__ void scan3_kernel(const int* __restrict__ tmp, const int* __restrict__ bsum,
                             const int* __restrict__ deg,
                             int* __restrict__ row_ptr, int* __restrict__ cursor) {
    int i = blockIdx.x * 256 + threadIdx.x;
    if (i >= Nn) return;
    int boff = (blockIdx.x == 0) ? 0 : bsum[blockIdx.x - 1];
    int incl = tmp[i] + boff;
    row_ptr[i + 1] = incl;
    cursor[i] = incl - deg[i];
    if (i == 0) row_ptr[0] = 0;
}

__global__ void scatter_kernel(const int* __restrict__ ei, int* __restrict__ cursor,
                               int* __restrict__ csr_src) {
    int e = blockIdx.x * blockDim.x + threadIdx.x;
    if (e >= ETOT) return;
    int s, d; decode_edge(ei, e, s, d);
    int pos = atomicAdd(&cursor[d], 1);
    csr_src[pos] = s;
}

// ---------------- casts ----------------

__global__ void cast_kernel(const float* __restrict__ in, __bf16* __restrict__ out, int n4) {
    int i = blockIdx.x * blockDim.x + threadIdx.x;
    if (i >= n4) return;
    f32x4 v = ((const f32x4*)in)[i];
    bf16x4 o;
    #pragma unroll
    for (int k = 0; k < 4; ++k) o[k] = (__bf16)v[k];
    ((bf16x4*)out)[i] = o;
}

// W[K][N] fp32 -> WT[N][K] bf16; grid.z selects matrix (stride K*N)
__global__ void transpose_cast_kernel(const float* __restrict__ W, __bf16* __restrict__ WT,
                                      int K, int N) {
    __shared__ float tile[32][33];
    W  += (size_t)blockIdx.z * K * N;
    WT += (size_t)blockIdx.z * K * N;
    int n0 = blockIdx.x * 32, k0 = blockIdx.y * 32;
    for (int i = threadIdx.y; i < 32; i += 8)
        tile[i][threadIdx.x] = W[(size_t)(k0 + i) * N + n0 + threadIdx.x];
    __syncthreads();
    for (int i = threadIdx.y; i < 32; i += 8)
        WT[(size_t)(n0 + i) * K + k0 + threadIdx.x] = (__bf16)tile[threadIdx.x][i];
}

// ---------------- w~ precompute: wt[l][k][8] = {W_l[k,:head-slice].att_{s,d}[h]} ----------------
// alpha_src[n,h] = h[n,:].att_s[h] = (A @ W).att_s = A @ (W @ att_s) — exact algebra.

__global__ __launch_bounds__(256) void wtilde_kernel(const float* __restrict__ W0,
                                                     const float* __restrict__ W_rest,
                                                     const float* __restrict__ att_src,
                                                     const float* __restrict__ att_dst,
                                                     __bf16* __restrict__ wt) {
    int g = blockIdx.x * 4 + (threadIdx.x >> 6);
    int lane = threadIdx.x & 63;
    if (g >= 3584) return;
    int l, k;
    const float* row;
    if (g < 512) { l = 0; k = g; row = W0 + (size_t)k * HC; }
    else {
        int gg = g - 512; l = 1 + (gg >> 10); k = gg & 1023;
        row = W_rest + (size_t)(l - 1) * HC * HC + (size_t)k * HC;
    }
    const float* as = att_src + l * HC;   // [4][256]
    const float* ad = att_dst + l * HC;
    int c0 = lane * 16;
    int head = lane >> 4;                 // 16 lanes per head
    float s = 0.f, d = 0.f;
    #pragma unroll
    for (int c = 0; c < 16; ++c) {
        float w = row[c0 + c];
        s += w * as[c0 + c];
        d += w * ad[c0 + c];
    }
    #pragma unroll
    for (int off = 1; off < 16; off <<= 1) {
        s += __shfl_xor(s, off);
        d += __shfl_xor(d, off);
    }
    if ((lane & 15) == 0) {
        wt[((size_t)l * 1024 + k) * 8 + head * 2]     = (__bf16)s;
        wt[((size_t)l * 1024 + k) * 8 + head * 2 + 1] = (__bf16)d;
    }
}

// ---------------- alpha GEMV (per layer): asrc/adst[n][h] = A[n,:] @ wt_l ----------------
// r11-proven: 13us/layer at ~3 TB/s. Fusing this into agg's epilogue was tried
// (r12/r13) and REGRESSED: +4 VGPR + 32 shfl_xor cut agg occupancy 76->66%,
// costing ~130us across layers vs the 39us this kernel costs. Keep standalone.

__global__ __launch_bounds__(256) void alpha_gemv_kernel(const __bf16* __restrict__ A,
                                                         const __bf16* __restrict__ wt_l,
                                                         float* __restrict__ asrc,
                                                         float* __restrict__ adst, int K) {
    int n = blockIdx.x * 4 + (threadIdx.x >> 6);
    int lane = threadIdx.x & 63;
    if (n >= Nn) return;
    float acc[8] = {};
    for (int k0 = lane * 8; k0 < K; k0 += 512) {
        bf16x8 av = *(const bf16x8*)(A + (size_t)n * K + k0);
        #pragma unroll
        for (int kk = 0; kk < 8; ++kk) {
            float af = (float)av[kk];
            bf16x8 wv = *(const bf16x8*)(wt_l + (size_t)(k0 + kk) * 8);
            #pragma unroll
            for (int j = 0; j < 8; ++j) acc[j] += af * (float)wv[j];
        }
    }
    #pragma unroll
    for (int off = 32; off > 0; off >>= 1)
        #pragma unroll
        for (int j = 0; j < 8; ++j) acc[j] += __shfl_down(acc[j], off);
    if (lane == 0) {
        #pragma unroll
        for (int h = 0; h < 4; ++h) {
            asrc[n * 4 + h] = acc[h * 2];
            adst[n * 4 + h] = acc[h * 2 + 1];
        }
    }
}

// ---------------- MFMA GEMM: C8[M,1024](fp8) = A[M,K](bf16) @ BT[1024,K]^T ----------------
// XCD swizzle: all 8 col-blocks of a row-group land on one XCD (r11: FETCH 162->34MB).

__device__ __forceinline__ void async16(const __bf16* g, __bf16* l) {
    __builtin_amdgcn_global_load_lds((const __attribute__((address_space(1))) void*)g,
                                     (__attribute__((address_space(3))) void*)l,
                                     16, 0, 0);
}

__global__ __launch_bounds__(256) void mfma_gemm_kernel(
    const __bf16* __restrict__ A,   // [M][K]
    const __bf16* __restrict__ BT,  // [1024][K]
    unsigned char* __restrict__ C8, // [M][1024] fp8 e4m3 (agg gather payload)
    int M, int K)
{
    int lin = blockIdx.y * 8 + blockIdx.x;          // grid (8, 160) -> 1280 ids
    int rblk = (lin >> 6) * 8 + (lin & 7);
    int cblk = (lin >> 3) & 7;
    int rowBase = rblk * 128, colBase = cblk * 128;
    if (rowBase >= M) return;

    __shared__ __bf16 As[2][128 * 32];
    __shared__ __bf16 Bs[2][128 * 32];
    int tid = threadIdx.x;
    int wave = tid >> 6, lane = tid & 63;
    int m16 = lane & 15, quad = lane >> 4;
    int waveRow = (wave >> 1) * 64, waveCol = (wave & 1) * 64;

    f32x4 acc[4][4] = {};

    int srow = wave * 32 + (lane >> 2);          // staging row, +16 for second half
    int gch0 = (lane & 3) ^ ((srow >> 1) & 3);
    int gch1 = (lane & 3) ^ (((srow + 16) >> 1) & 3);
    int gr0 = rowBase + srow;       if (gr0 >= M) gr0 = M - 1;
    int gr1 = rowBase + srow + 16;  if (gr1 >= M) gr1 = M - 1;
    int ldsOff = srow * 32 + (lane & 3) * 8;

    for (int k0 = 0; k0 < K; k0 += 64) {
        #pragma unroll
        for (int p = 0; p < 2; ++p) {
            int kp = k0 + p * 32;
            async16(A + (size_t)gr0 * K + kp + gch0 * 8, &As[p][ldsOff]);
            async16(A + (size_t)gr1 * K + kp + gch1 * 8, &As[p][ldsOff + 16 * 32]);
            async16(BT + (size_t)(colBase + srow) * K + kp + gch0 * 8, &Bs[p][ldsOff]);
            async16(BT + (size_t)(colBase + srow + 16) * K + kp + gch1 * 8, &Bs[p][ldsOff + 16 * 32]);
        }
        __syncthreads();
        #pragma unroll
        for (int p = 0; p < 2; ++p) {
            bf16x8 af[4], bfr[4];
            #pragma unroll
            for (int i = 0; i < 4; ++i) {
                int row = waveRow + i * 16 + m16;
                af[i] = *(const bf16x8*)&As[p][row * 32 + (quad ^ ((row >> 1) & 3)) * 8];
                int col = waveCol + i * 16 + m16;
                bfr[i] = *(const bf16x8*)&Bs[p][col * 32 + (quad ^ ((col >> 1) & 3)) * 8];
            }
            #pragma unroll
            for (int i = 0; i < 4; ++i)
                #pragma unroll
                for (int j = 0; j < 4; ++j)
                    acc[i][j] = __builtin_amdgcn_mfma_f32_16x16x32_bf16(af[i], bfr[j], acc[i][j], 0, 0, 0);
        }
        __syncthreads();
    }

    // lean epilogue: fp8 stores (C/D layout: col=lane&15, row=quad*4+reg)
    #pragma unroll
    for (int i = 0; i < 4; ++i) {
        int r0 = rowBase + waveRow + i * 16 + quad * 4;
        #pragma unroll
        for (int r = 0; r < 4; ++r) {
            int row = r0 + r;
            if (row < M) {
                #pragma unroll
                for (int j = 0; j < 4; ++j)
                    C8[(size_t)row * HC + colBase + waveCol + j * 16 + m16] =
                        f32_to_fp8(acc[i][j][r]);
            }
        }
    }
}

// ---------------- edge-weight precompute (head-major output) ----------------

__global__ __launch_bounds__(256) void ew_kernel(const float* __restrict__ asrc,
                                                 const float* __restrict__ adst,
                                                 const int* __restrict__ row_ptr,
                                                 const int* __restrict__ csr_src,
                                                 float* __restrict__ ewT,
                                                 float* __restrict__ dinv) {
    int w = threadIdx.x >> 6, lane = threadIdx.x & 63;
    int n = blockIdx.x * 4 + w;
    if (n >= Nn) return;
    int start = row_ptr[n], end = row_ptr[n + 1];
    f32x4 ad = ((const f32x4*)adst)[n];
    f32x4 d = {0.f, 0.f, 0.f, 0.f};
    for (int e = start + lane; e < end; e += 64) {
        int s = csr_src[e];
        f32x4 as = ((const f32x4*)asrc)[s];
        #pragma unroll
        for (int k = 0; k < 4; ++k) {
            float z = as[k] + ad[k];
            z = (z > 0.f) ? z : NEG_SLOPE * z;
            float ex = __expf(z);
            ewT[(size_t)k * ETOT + e] = ex;
            d[k] += ex;
        }
    }
    #pragma unroll
    for (int off = 32; off > 0; off >>= 1) {
        #pragma unroll
        for (int k = 0; k < 4; ++k) d[k] += __shfl_down(d[k], off);
    }
    if (lane == 0) {
        f32x4 iv;
        #pragma unroll
        for (int k = 0; k < 4; ++k) iv[k] = 1.f / (d[k] + 1e-16f);
        ((f32x4*)dinv)[n] = iv;
    }
}

// ---------------- sliced aggregation (r11-proven: fp8, 8 ch/thread, 2-wide) ----------------
// grid (8, 1250): slice -> XCD affinity; per-XCD footprint 2.5MB (96% L2 hit, r10).
// Block = 16 node-slots x 16 ch-threads; each thread serially walks ITS node's
// edges for 8 fp8 channels (8B loads). No fused epilogue (r12/r13 regression).

__global__ __launch_bounds__(256) void agg_slice_kernel(
    const unsigned char* __restrict__ h8,
    const float* __restrict__ ewT,
    const float* __restrict__ dinv,
    const int* __restrict__ row_ptr,
    const int* __restrict__ csr_src,
    const float* __restrict__ bias_l,
    __bf16* __restrict__ outb)
{
    int slice = blockIdx.x;              // 0..7
    int head = slice >> 1;
    int tid = threadIdx.x;
    int nslot = tid >> 4;                // 0..15
    int ch = tid & 15;                   // 8B fp8 group within 128B slice
    int n = blockIdx.y * 16 + nslot;

    __shared__ int   csr_sh[512];
    __shared__ float ew_sh[512];
    __shared__ int   rp_sh[17];

    if (tid < 17) rp_sh[tid] = row_ptr[blockIdx.y * 16 + tid];
    __syncthreads();
    int blk_lo = rp_sh[0], blk_hi = rp_sh[16];
    int start = rp_sh[nslot], end = rp_sh[nslot + 1];

    const unsigned char* hs = h8 + slice * 128 + ch * 8;
    const float* ewh = ewT + (size_t)head * ETOT;
    float acc[8] = {};

    for (int c0 = blk_lo; c0 < blk_hi; c0 += 512) {
        int c1 = min(c0 + 512, blk_hi);
        int cnt = c1 - c0;
        for (int i = tid; i < cnt; i += 256) {     // coalesced stage
            csr_sh[i] = csr_src[c0 + i];
            ew_sh[i]  = ewh[c0 + i];
        }
        __syncthreads();
        int lo = max(start, c0), hi = min(end, c1);
        int e = lo;
        for (; e + 1 < hi; e += 2) {
            int s0 = csr_sh[e - c0], s1 = csr_sh[e + 1 - c0];
            float w0 = ew_sh[e - c0], w1 = ew_sh[e + 1 - c0];
            uint2 u0 = *(const uint2*)(hs + (size_t)s0 * HC);
            uint2 u1 = *(const uint2*)(hs + (size_t)s1 * HC);
            f32x4 a0 = fp8x4_to_f32(u0.x), b0 = fp8x4_to_f32(u0.y);
            f32x4 a1 = fp8x4_to_f32(u1.x), b1 = fp8x4_to_f32(u1.y);
            #pragma unroll
            for (int k = 0; k < 4; ++k) {
                acc[k]     += w0 * a0[k];
                acc[k + 4] += w0 * b0[k];
                acc[k]     += w1 * a1[k];
                acc[k + 4] += w1 * b1[k];
            }
        }
        if (e < hi) {
            int s0 = csr_sh[e - c0];
            float w0 = ew_sh[e - c0];
            uint2 u0 = *(const uint2*)(hs + (size_t)s0 * HC);
            f32x4 a0 = fp8x4_to_f32(u0.x), b0 = fp8x4_to_f32(u0.y);
            #pragma unroll
            for (int k = 0; k < 4; ++k) {
                acc[k]     += w0 * a0[k];
                acc[k + 4] += w0 * b0[k];
            }
        }
        __syncthreads();
    }

    float inv = dinv[n * 4 + head];
    bf16x8 o;
    #pragma unroll
    for (int k = 0; k < 8; ++k)
        o[k] = (__bf16)fmaxf(acc[k] * inv + bias_l[slice * 128 + ch * 8 + k], 0.f);
    *(bf16x8*)(outb + (size_t)n * HC + slice * 128 + ch * 8) = o;
}

// ---------------- global mean pool (race-free partials) ----------------

__device__ __forceinline__ int lower_bound_batch(const int* __restrict__ batch, int val) {
    int lo = 0, hi = Nn;
    while (lo < hi) { int mid = (lo + hi) >> 1; if (batch[mid] < val) lo = mid + 1; else hi = mid; }
    return lo;
}

__global__ void pool_kernel(const __bf16* __restrict__ h2b, const int* __restrict__ batch,
                            float* __restrict__ pooledP) {
    int b = blockIdx.x, part = blockIdx.y;   // grid (B, 8)
    int tid = threadIdx.x;
    int start = lower_bound_batch(batch, b);
    int end   = lower_bound_batch(batch, b + 1);
    int len = end - start;
    int chunk = (len + 7) / 8;
    int s0 = start + part * chunk;
    int s1 = min(s0 + chunk, end);
    float acc[4] = {0.f, 0.f, 0.f, 0.f};
    for (int n = s0; n < s1; ++n) {
        bf16x4 v = ((const bf16x4*)(h2b + (size_t)n * HC))[tid];
        #pragma unroll
        for (int k = 0; k < 4; ++k) acc[k] += (float)v[k];
    }
    #pragma unroll
    for (int k = 0; k < 4; ++k)
        pooledP[((size_t)part * Bb + b) * HC + tid * 4 + k] = acc[k];
}

// ---------------- projection (k-split, race-free partials) + layernorm ----------------

__global__ __launch_bounds__(512) void proj_partial_kernel(const float* __restrict__ pooledP,
                                                           const int* __restrict__ batch,
                                                           const float* __restrict__ projW,
                                                           float* __restrict__ projP) {
    int b = blockIdx.x, part = blockIdx.y;   // grid (16, 8)
    int d = threadIdx.x;                     // 512
    __shared__ float psum[HC];
    int start = lower_bound_batch(batch, b);
    int end   = lower_bound_batch(batch, b + 1);
    float inv = 1.0f / fmaxf((float)(end - start), 1.0f);
    for (int k = d; k < HC; k += 512) {
        float s = 0.f;
        #pragma unroll
        for (int p = 0; p < 8; ++p) s += pooledP[((size_t)p * Bb + b) * HC + k];
        psum[k] = s * inv;
    }
    __syncthreads();
    float acc = 0.f;
    int k0 = part * 128;
    for (int k = k0; k < k0 + 128; ++k)
        acc += psum[k] * projW[(size_t)k * Dd + d];
    projP[((size_t)part * Bb + b) * Dd + d] = acc;
}

__global__ __launch_bounds__(512) void ln_kernel(const float* __restrict__ projP,
                                                 const float* __restrict__ projb,
                                                 const float* __restrict__ gamma,
                                                 const float* __restrict__ beta,
                                                 float* __restrict__ out) {
    int b = blockIdx.x;
    int d = threadIdx.x;
    __shared__ float red[512];
    float o = projb[d];
    #pragma unroll
    for (int p = 0; p < 8; ++p) o += projP[((size_t)p * Bb + b) * Dd + d];
    red[d] = o;
    __syncthreads();
    for (int off = 256; off > 0; off >>= 1) {
        if (d < off) red[d] += red[d + off];
        __syncthreads();
    }
    float mu = red[0] / (float)Dd;
    __syncthreads();
    float df = o - mu;
    red[d] = df * df;
    __syncthreads();
    for (int off = 256; off > 0; off >>= 1) {
        if (d < off) red[d] += red[d + off];
        __syncthreads();
    }
    float var = red[0] / (float)Dd;
    out[b * Dd + d] = df / sqrtf(var + LN_EPS) * gamma[d] + beta[d];
}

// ---------------- launch ----------------

extern "C" void kernel_launch(void* const* d_in, const int* in_sizes, int n_in,
                              void* d_out, int out_size, void* d_ws, size_t ws_size,
                              hipStream_t stream) {
    const float* x         = (const float*)d_in[0];
    const int*   ei        = (const int*)d_in[1];
    const int*   batch     = (const int*)d_in[2];
    const float* W0        = (const float*)d_in[3];
    const float* W_rest    = (const float*)d_in[4];
    const float* att_src   = (const float*)d_in[5];
    const float* att_dst   = (const float*)d_in[6];
    const float* conv_bias = (const float*)d_in[7];
    const float* proj_W    = (const float*)d_in[8];
    const float* proj_b    = (const float*)d_in[9];
    const float* ln_gamma  = (const float*)d_in[10];
    const float* ln_beta   = (const float*)d_in[11];
    float* out = (float*)d_out;

    char* ws = (char*)d_ws;
    size_t off = 0;
    auto alloc = [&](size_t bytes) {
        void* p = ws + off;
        off = (off + bytes + 255) & ~(size_t)255;
        return p;
    };
    unsigned char* h8 = (unsigned char*)alloc((size_t)Nn * HC);   // GEMM out (fp8, agg payload)
    __bf16* h2b     = (__bf16*)alloc((size_t)Nn * HC * 2);        // layer out (bf16)
    __bf16* xb      = (__bf16*)alloc((size_t)Nn * Dd * 2);
    __bf16* W0T     = (__bf16*)alloc((size_t)HC * Dd * 2);
    __bf16* WrT     = (__bf16*)alloc((size_t)3 * HC * HC * 2);
    __bf16* wt      = (__bf16*)alloc((size_t)4 * 1024 * 8 * 2);   // w~ per layer
    float*  asrc    = (float*)alloc((size_t)Nn * Hh * 4);
    float*  adst    = (float*)alloc((size_t)Nn * Hh * 4);
    float*  ewT     = (float*)alloc((size_t)Hh * ETOT * 4);       // head-major
    float*  dinv    = (float*)alloc((size_t)Nn * Hh * 4);
    int*    deg     = (int*)alloc((size_t)Nn * 4);
    int*    tmp     = (int*)alloc((size_t)Nn * 4);
    int*    bsum    = (int*)alloc((size_t)256 * 4);
    int*    row_ptr = (int*)alloc((size_t)(Nn + 1) * 4);
    int*    cursor  = (int*)alloc((size_t)Nn * 4);
    int*    csr_src = (int*)alloc((size_t)ETOT * 4);
    float*  pooledP = (float*)alloc((size_t)8 * Bb * HC * 4);
    float*  projP   = (float*)alloc((size_t)8 * Bb * Dd * 4);
    (void)ws_size; (void)in_sizes; (void)n_in; (void)out_size;

    // ---- build CSR by destination ----
    hipMemsetAsync(deg, 0, (size_t)Nn * 4, stream);
    count_deg_kernel<<<(ETOT + 255) / 256, 256, 0, stream>>>(ei, deg);
    scan1_kernel<<<NBLK, 256, 0, stream>>>(deg, tmp, bsum);
    scan2_kernel<<<1, 256, 0, stream>>>(bsum);
    scan3_kernel<<<NBLK, 256, 0, stream>>>(tmp, bsum, deg, row_ptr, cursor);
    scatter_kernel<<<(ETOT + 255) / 256, 256, 0, stream>>>(ei, cursor, csr_src);

    // ---- bf16 casts / weight transposes / w~ ----
    cast_kernel<<<(Nn * Dd / 4 + 255) / 256, 256, 0, stream>>>(x, xb, Nn * Dd / 4);
    transpose_cast_kernel<<<dim3(HC / 32, Dd / 32, 1), dim3(32, 8), 0, stream>>>(W0, W0T, Dd, HC);
    transpose_cast_kernel<<<dim3(HC / 32, HC / 32, 3), dim3(32, 8), 0, stream>>>(W_rest, WrT, HC, HC);
    wtilde_kernel<<<(3584 + 3) / 4, 256, 0, stream>>>(W0, W_rest, att_src, att_dst, wt);

    // ---- GAT layers ----
    dim3 gemm_grid(8, 160);   // 1280 swizzled ids -> (157 row-blocks, 8 col-blocks)
    for (int l = 0; l < Ll; ++l) {
        const __bf16* Afeat = (l == 0) ? xb : h2b;
        int K = (l == 0) ? Dd : HC;
        const __bf16* BT = (l == 0) ? W0T : (WrT + (size_t)(l - 1) * HC * HC);
        alpha_gemv_kernel<<<(Nn + 3) / 4, 256, 0, stream>>>(
            Afeat, wt + (size_t)l * 1024 * 8, asrc, adst, K);
        mfma_gemm_kernel<<<gemm_grid, 256, 0, stream>>>(Afeat, BT, h8, Nn, K);
        ew_kernel<<<(Nn + 3) / 4, 256, 0, stream>>>(asrc, adst, row_ptr, csr_src, ewT, dinv);
        agg_slice_kernel<<<dim3(8, Nn / 16), 256, 0, stream>>>(
            h8, ewT, dinv, row_ptr, csr_src, conv_bias + l * HC, h2b);
    }

    // ---- pool + proj + layernorm (all race-free partials, no memsets) ----
    pool_kernel<<<dim3(Bb, 8), 256, 0, stream>>>(h2b, batch, pooledP);
    proj_partial_kernel<<<dim3(Bb, 8), 512, 0, stream>>>(pooledP, batch, proj_W, projP);
    ln_kernel<<<Bb, 512, 0, stream>>>(projP, proj_b, ln_gamma, ln_beta, out);
}

// Round 15
// 673.321 us; speedup vs baseline: 1.1751x; 1.1751x over previous
//
#include <hip/hip_runtime.h>
#include <hip/hip_bf16.h>
#include <hip/hip_fp8.h>
#include <math.h>

#define Nn 20000
#define Ee 320000
#define Dd 512
#define Hh 4
#define Cc 256
#define Ll 4
#define Bb 16
#define HC 1024               // H*C
#define ETOT (Ee + Nn)        // edges + self loops = 340000
#define NEG_SLOPE 0.2f
#define LN_EPS 1e-5f
#define NBLK ((Nn + 255) / 256)   // 79 scan blocks

typedef __attribute__((ext_vector_type(8))) __bf16 bf16x8;
typedef __attribute__((ext_vector_type(4))) __bf16 bf16x4;
typedef __attribute__((ext_vector_type(4))) float f32x4;
typedef __attribute__((ext_vector_type(2))) float f32x2;

// fp8 e4m3 (OCP) x4 decode — HW packed cvt if available
__device__ __forceinline__ f32x4 fp8x4_to_f32(unsigned int v) {
#if __has_builtin(__builtin_amdgcn_cvt_pk_f32_fp8)
    f32x2 lo = __builtin_amdgcn_cvt_pk_f32_fp8((int)v, false);
    f32x2 hi = __builtin_amdgcn_cvt_pk_f32_fp8((int)v, true);
    f32x4 r; r[0] = lo[0]; r[1] = lo[1]; r[2] = hi[0]; r[3] = hi[1];
    return r;
#else
    f32x4 r;
    #pragma unroll
    for (int i = 0; i < 4; ++i) {
        __hip_fp8_e4m3 q; q.__x = (v >> (8 * i)) & 0xff;
        r[i] = (float)q;
    }
    return r;
#endif
}

__device__ __forceinline__ unsigned char f32_to_fp8(float f) {
    return __hip_fp8_e4m3(f).__x;
}

// ---------------- CSR build ----------------

__device__ __forceinline__ void decode_edge(const int* ei, int e, int& s, int& d) {
    if (e < Ee) { s = ei[e]; d = ei[Ee + e]; }
    else        { s = e - Ee; d = e - Ee; }   // self loop
}

__global__ void count_deg_kernel(const int* __restrict__ ei, int* __restrict__ deg) {
    int e = blockIdx.x * blockDim.x + threadIdx.x;
    if (e >= ETOT) return;
    int s, d; decode_edge(ei, e, s, d);
    atomicAdd(&deg[d], 1);
}

__global__ void scan1_kernel(const int* __restrict__ deg, int* __restrict__ tmp,
                             int* __restrict__ bsum) {
    __shared__ int sd[256];
    int tid = threadIdx.x;
    int i = blockIdx.x * 256 + tid;
    sd[tid] = (i < Nn) ? deg[i] : 0;
    __syncthreads();
    for (int off = 1; off < 256; off <<= 1) {
        int t = (tid >= off) ? sd[tid - off] : 0;
        __syncthreads();
        sd[tid] += t;
        __syncthreads();
    }
    if (i < Nn) tmp[i] = sd[tid];
    if (tid == 255) bsum[blockIdx.x] = sd[255];
}

__global__ void scan2_kernel(int* __restrict__ bsum) {   // single block, NBLK<=256
    __shared__ int sd[256];
    int tid = threadIdx.x;
    sd[tid] = (tid < NBLK) ? bsum[tid] : 0;
    __syncthreads();
    for (int off = 1; off < 256; off <<= 1) {
        int t = (tid >= off) ? sd[tid - off] : 0;
        __syncthreads();
        sd[tid] += t;
        __syncthreads();
    }
    if (tid < NBLK) bsum[tid] = sd[tid];
}

__global__ void scan3_kernel(const int* __restrict__ tmp, const int* __restrict__ bsum,
                             const int* __restrict__ deg,
                             int* __restrict__ row_ptr, int* __restrict__ cursor) {
    int i = blockIdx.x * 256 + threadIdx.x;
    if (i >= Nn) return;
    int boff = (blockIdx.x == 0) ? 0 : bsum[blockIdx.x - 1];
    int incl = tmp[i] + boff;
    row_ptr[i + 1] = incl;
    cursor[i] = incl - deg[i];
    if (i == 0) row_ptr[0] = 0;
}

__global__ void scatter_kernel(const int* __restrict__ ei, int* __restrict__ cursor,
                               int* __restrict__ csr_src) {
    int e = blockIdx.x * blockDim.x + threadIdx.x;
    if (e >= ETOT) return;
    int s, d; decode_edge(ei, e, s, d);
    int pos = atomicAdd(&cursor[d], 1);
    csr_src[pos] = s;
}

// ---------------- casts ----------------

__global__ void cast_kernel(const float* __restrict__ in, __bf16* __restrict__ out, int n4) {
    int i = blockIdx.x * blockDim.x + threadIdx.x;
    if (i >= n4) return;
    f32x4 v = ((const f32x4*)in)[i];
    bf16x4 o;
    #pragma unroll
    for (int k = 0; k < 4; ++k) o[k] = (__bf16)v[k];
    ((bf16x4*)out)[i] = o;
}

// W[K][N] fp32 -> WT[N][K] bf16; grid.z selects matrix (stride K*N)
__global__ void transpose_cast_kernel(const float* __restrict__ W, __bf16* __restrict__ WT,
                                      int K, int N) {
    __shared__ float tile[32][33];
    W  += (size_t)blockIdx.z * K * N;
    WT += (size_t)blockIdx.z * K * N;
    int n0 = blockIdx.x * 32, k0 = blockIdx.y * 32;
    for (int i = threadIdx.y; i < 32; i += 8)
        tile[i][threadIdx.x] = W[(size_t)(k0 + i) * N + n0 + threadIdx.x];
    __syncthreads();
    for (int i = threadIdx.y; i < 32; i += 8)
        WT[(size_t)(n0 + i) * K + k0 + threadIdx.x] = (__bf16)tile[threadIdx.x][i];
}

// ---------------- MFMA GEMM + fused alpha epilogue ----------------
// C8[M,1024](fp8) = A[M,K](bf16) @ BT[1024,K]^T. XCD swizzle (r11: FETCH 162->34MB).
// Epilogue computes alpha partials ps/pd = sum_j h*att from IN-REGISTER h (zero
// extra traffic — the r14 standalone gemv re-read 40MB and cost ~25-30us/layer).
// Race-free: part=(cblk&1)*2+(wave&1) — for fixed (row,head) the 4 writers
// (cblk in {2h,2h+1} x wave&1) get distinct parts. No atomics, no pre-zeroing.

__device__ __forceinline__ void async16(const __bf16* g, __bf16* l) {
    __builtin_amdgcn_global_load_lds((const __attribute__((address_space(1))) void*)g,
                                     (__attribute__((address_space(3))) void*)l,
                                     16, 0, 0);
}

__global__ __launch_bounds__(256) void mfma_gemm_kernel(
    const __bf16* __restrict__ A,   // [M][K]
    const __bf16* __restrict__ BT,  // [1024][K]
    unsigned char* __restrict__ C8, // [M][1024] fp8 e4m3 (agg gather payload)
    const float* __restrict__ att_s,  // [4][256] this layer
    const float* __restrict__ att_d,  // [4][256]
    float* __restrict__ aprt_s,     // [4][M][4] partials (race-free)
    float* __restrict__ aprt_d,     // [4][M][4]
    int M, int K)
{
    int lin = blockIdx.y * 8 + blockIdx.x;          // grid (8, 160) -> 1280 ids
    int rblk = (lin >> 6) * 8 + (lin & 7);
    int cblk = (lin >> 3) & 7;
    int rowBase = rblk * 128, colBase = cblk * 128;
    if (rowBase >= M) return;

    __shared__ __bf16 As[2][128 * 32];
    __shared__ __bf16 Bs[2][128 * 32];
    int tid = threadIdx.x;
    int wave = tid >> 6, lane = tid & 63;
    int m16 = lane & 15, quad = lane >> 4;
    int waveRow = (wave >> 1) * 64, waveCol = (wave & 1) * 64;

    f32x4 acc[4][4] = {};

    int srow = wave * 32 + (lane >> 2);          // staging row, +16 for second half
    int gch0 = (lane & 3) ^ ((srow >> 1) & 3);
    int gch1 = (lane & 3) ^ (((srow + 16) >> 1) & 3);
    int gr0 = rowBase + srow;       if (gr0 >= M) gr0 = M - 1;
    int gr1 = rowBase + srow + 16;  if (gr1 >= M) gr1 = M - 1;
    int ldsOff = srow * 32 + (lane & 3) * 8;

    for (int k0 = 0; k0 < K; k0 += 64) {
        #pragma unroll
        for (int p = 0; p < 2; ++p) {
            int kp = k0 + p * 32;
            async16(A + (size_t)gr0 * K + kp + gch0 * 8, &As[p][ldsOff]);
            async16(A + (size_t)gr1 * K + kp + gch1 * 8, &As[p][ldsOff + 16 * 32]);
            async16(BT + (size_t)(colBase + srow) * K + kp + gch0 * 8, &Bs[p][ldsOff]);
            async16(BT + (size_t)(colBase + srow + 16) * K + kp + gch1 * 8, &Bs[p][ldsOff + 16 * 32]);
        }
        __syncthreads();
        #pragma unroll
        for (int p = 0; p < 2; ++p) {
            bf16x8 af[4], bfr[4];
            #pragma unroll
            for (int i = 0; i < 4; ++i) {
                int row = waveRow + i * 16 + m16;
                af[i] = *(const bf16x8*)&As[p][row * 32 + (quad ^ ((row >> 1) & 3)) * 8];
                int col = waveCol + i * 16 + m16;
                bfr[i] = *(const bf16x8*)&Bs[p][col * 32 + (quad ^ ((col >> 1) & 3)) * 8];
            }
            #pragma unroll
            for (int i = 0; i < 4; ++i)
                #pragma unroll
                for (int j = 0; j < 4; ++j)
                    acc[i][j] = __builtin_amdgcn_mfma_f32_16x16x32_bf16(af[i], bfr[j], acc[i][j], 0, 0, 0);
        }
        __syncthreads();
    }

    // att weights for this wave's 64-col span (single head: span never crosses 256)
    int cbase = colBase + waveCol;
    int head = cbase >> 8;
    int part = (cblk & 1) * 2 + (wave & 1);
    float as4[4], ad4[4];
    #pragma unroll
    for (int j = 0; j < 4; ++j) {
        int off = (cbase + j * 16 + m16) & 255;
        as4[j] = att_s[head * 256 + off];
        ad4[j] = att_d[head * 256 + off];
    }

    // fp8 stores (C/D layout: col=lane&15, row=quad*4+reg) + alpha partials
    #pragma unroll
    for (int i = 0; i < 4; ++i) {
        int r0 = rowBase + waveRow + i * 16 + quad * 4;
        #pragma unroll
        for (int r = 0; r < 4; ++r) {
            int row = r0 + r;
            float ps = 0.f, pd = 0.f;
            #pragma unroll
            for (int j = 0; j < 4; ++j) {
                float h = acc[i][j][r];
                ps += h * as4[j];
                pd += h * ad4[j];
                if (row < M)
                    C8[(size_t)row * HC + colBase + waveCol + j * 16 + m16] = f32_to_fp8(h);
            }
            #pragma unroll
            for (int off = 1; off < 16; off <<= 1) {
                ps += __shfl_xor(ps, off);
                pd += __shfl_xor(pd, off);
            }
            if (m16 == 0 && row < M) {
                aprt_s[((size_t)part * M + row) * 4 + head] = ps;
                aprt_d[((size_t)part * M + row) * 4 + head] = pd;
            }
        }
    }
}

// ---------------- alpha partial reduce: asrc/adst[n] = sum over 4 parts ----------------

__global__ void alpha_sum_kernel(const float* __restrict__ aprt_s,
                                 const float* __restrict__ aprt_d,
                                 float* __restrict__ asrc, float* __restrict__ adst) {
    int n = blockIdx.x * 256 + threadIdx.x;
    if (n >= Nn) return;
    f32x4 s = {0.f, 0.f, 0.f, 0.f}, d = {0.f, 0.f, 0.f, 0.f};
    #pragma unroll
    for (int p = 0; p < 4; ++p) {
        f32x4 vs = ((const f32x4*)aprt_s)[(size_t)p * Nn + n];
        f32x4 vd = ((const f32x4*)aprt_d)[(size_t)p * Nn + n];
        #pragma unroll
        for (int k = 0; k < 4; ++k) { s[k] += vs[k]; d[k] += vd[k]; }
    }
    ((f32x4*)asrc)[n] = s;
    ((f32x4*)adst)[n] = d;
}

// ---------------- edge-weight precompute (head-major output) ----------------

__global__ __launch_bounds__(256) void ew_kernel(const float* __restrict__ asrc,
                                                 const float* __restrict__ adst,
                                                 const int* __restrict__ row_ptr,
                                                 const int* __restrict__ csr_src,
                                                 float* __restrict__ ewT,
                                                 float* __restrict__ dinv) {
    int w = threadIdx.x >> 6, lane = threadIdx.x & 63;
    int n = blockIdx.x * 4 + w;
    if (n >= Nn) return;
    int start = row_ptr[n], end = row_ptr[n + 1];
    f32x4 ad = ((const f32x4*)adst)[n];
    f32x4 d = {0.f, 0.f, 0.f, 0.f};
    for (int e = start + lane; e < end; e += 64) {
        int s = csr_src[e];
        f32x4 as = ((const f32x4*)asrc)[s];
        #pragma unroll
        for (int k = 0; k < 4; ++k) {
            float z = as[k] + ad[k];
            z = (z > 0.f) ? z : NEG_SLOPE * z;
            float ex = __expf(z);
            ewT[(size_t)k * ETOT + e] = ex;
            d[k] += ex;
        }
    }
    #pragma unroll
    for (int off = 32; off > 0; off >>= 1) {
        #pragma unroll
        for (int k = 0; k < 4; ++k) d[k] += __shfl_down(d[k], off);
    }
    if (lane == 0) {
        f32x4 iv;
        #pragma unroll
        for (int k = 0; k < 4; ++k) iv[k] = 1.f / (d[k] + 1e-16f);
        ((f32x4*)dinv)[n] = iv;
    }
}

// ---------------- sliced aggregation (r11-proven: fp8, 8 ch/thread, 2-wide) ----------------
// grid (8, 1250): slice -> XCD affinity; per-XCD footprint 2.5MB (96% L2 hit, r10).
// Block = 16 node-slots x 16 ch-threads; each thread serially walks ITS node's
// edges for 8 fp8 channels (8B loads). No fused epilogue (r12/r13: latency-hiding loss).

__global__ __launch_bounds__(256) void agg_slice_kernel(
    const unsigned char* __restrict__ h8,
    const float* __restrict__ ewT,
    const float* __restrict__ dinv,
    const int* __restrict__ row_ptr,
    const int* __restrict__ csr_src,
    const float* __restrict__ bias_l,
    __bf16* __restrict__ outb)
{
    int slice = blockIdx.x;              // 0..7
    int head = slice >> 1;
    int tid = threadIdx.x;
    int nslot = tid >> 4;                // 0..15
    int ch = tid & 15;                   // 8B fp8 group within 128B slice
    int n = blockIdx.y * 16 + nslot;

    __shared__ int   csr_sh[512];
    __shared__ float ew_sh[512];
    __shared__ int   rp_sh[17];

    if (tid < 17) rp_sh[tid] = row_ptr[blockIdx.y * 16 + tid];
    __syncthreads();
    int blk_lo = rp_sh[0], blk_hi = rp_sh[16];
    int start = rp_sh[nslot], end = rp_sh[nslot + 1];

    const unsigned char* hs = h8 + slice * 128 + ch * 8;
    const float* ewh = ewT + (size_t)head * ETOT;
    float acc[8] = {};

    for (int c0 = blk_lo; c0 < blk_hi; c0 += 512) {
        int c1 = min(c0 + 512, blk_hi);
        int cnt = c1 - c0;
        for (int i = tid; i < cnt; i += 256) {     // coalesced stage
            csr_sh[i] = csr_src[c0 + i];
            ew_sh[i]  = ewh[c0 + i];
        }
        __syncthreads();
        int lo = max(start, c0), hi = min(end, c1);
        int e = lo;
        for (; e + 1 < hi; e += 2) {
            int s0 = csr_sh[e - c0], s1 = csr_sh[e + 1 - c0];
            float w0 = ew_sh[e - c0], w1 = ew_sh[e + 1 - c0];
            uint2 u0 = *(const uint2*)(hs + (size_t)s0 * HC);
            uint2 u1 = *(const uint2*)(hs + (size_t)s1 * HC);
            f32x4 a0 = fp8x4_to_f32(u0.x), b0 = fp8x4_to_f32(u0.y);
            f32x4 a1 = fp8x4_to_f32(u1.x), b1 = fp8x4_to_f32(u1.y);
            #pragma unroll
            for (int k = 0; k < 4; ++k) {
                acc[k]     += w0 * a0[k];
                acc[k + 4] += w0 * b0[k];
                acc[k]     += w1 * a1[k];
                acc[k + 4] += w1 * b1[k];
            }
        }
        if (e < hi) {
            int s0 = csr_sh[e - c0];
            float w0 = ew_sh[e - c0];
            uint2 u0 = *(const uint2*)(hs + (size_t)s0 * HC);
            f32x4 a0 = fp8x4_to_f32(u0.x), b0 = fp8x4_to_f32(u0.y);
            #pragma unroll
            for (int k = 0; k < 4; ++k) {
                acc[k]     += w0 * a0[k];
                acc[k + 4] += w0 * b0[k];
            }
        }
        __syncthreads();
    }

    float inv = dinv[n * 4 + head];
    bf16x8 o;
    #pragma unroll
    for (int k = 0; k < 8; ++k)
        o[k] = (__bf16)fmaxf(acc[k] * inv + bias_l[slice * 128 + ch * 8 + k], 0.f);
    *(bf16x8*)(outb + (size_t)n * HC + slice * 128 + ch * 8) = o;
}

// ---------------- global mean pool (race-free partials) ----------------

__device__ __forceinline__ int lower_bound_batch(const int* __restrict__ batch, int val) {
    int lo = 0, hi = Nn;
    while (lo < hi) { int mid = (lo + hi) >> 1; if (batch[mid] < val) lo = mid + 1; else hi = mid; }
    return lo;
}

__global__ void pool_kernel(const __bf16* __restrict__ h2b, const int* __restrict__ batch,
                            float* __restrict__ pooledP) {
    int b = blockIdx.x, part = blockIdx.y;   // grid (B, 8)
    int tid = threadIdx.x;
    int start = lower_bound_batch(batch, b);
    int end   = lower_bound_batch(batch, b + 1);
    int len = end - start;
    int chunk = (len + 7) / 8;
    int s0 = start + part * chunk;
    int s1 = min(s0 + chunk, end);
    float acc[4] = {0.f, 0.f, 0.f, 0.f};
    for (int n = s0; n < s1; ++n) {
        bf16x4 v = ((const bf16x4*)(h2b + (size_t)n * HC))[tid];
        #pragma unroll
        for (int k = 0; k < 4; ++k) acc[k] += (float)v[k];
    }
    #pragma unroll
    for (int k = 0; k < 4; ++k)
        pooledP[((size_t)part * Bb + b) * HC + tid * 4 + k] = acc[k];
}

// ---------------- projection (k-split, race-free partials) + layernorm ----------------

__global__ __launch_bounds__(512) void proj_partial_kernel(const float* __restrict__ pooledP,
                                                           const int* __restrict__ batch,
                                                           const float* __restrict__ projW,
                                                           float* __restrict__ projP) {
    int b = blockIdx.x, part = blockIdx.y;   // grid (16, 8)
    int d = threadIdx.x;                     // 512
    __shared__ float psum[HC];
    int start = lower_bound_batch(batch, b);
    int end   = lower_bound_batch(batch, b + 1);
    float inv = 1.0f / fmaxf((float)(end - start), 1.0f);
    for (int k = d; k < HC; k += 512) {
        float s = 0.f;
        #pragma unroll
        for (int p = 0; p < 8; ++p) s += pooledP[((size_t)p * Bb + b) * HC + k];
        psum[k] = s * inv;
    }
    __syncthreads();
    float acc = 0.f;
    int k0 = part * 128;
    for (int k = k0; k < k0 + 128; ++k)
        acc += psum[k] * projW[(size_t)k * Dd + d];
    projP[((size_t)part * Bb + b) * Dd + d] = acc;
}

__global__ __launch_bounds__(512) void ln_kernel(const float* __restrict__ projP,
                                                 const float* __restrict__ projb,
                                                 const float* __restrict__ gamma,
                                                 const float* __restrict__ beta,
                                                 float* __restrict__ out) {
    int b = blockIdx.x;
    int d = threadIdx.x;
    __shared__ float red[512];
    float o = projb[d];
    #pragma unroll
    for (int p = 0; p < 8; ++p) o += projP[((size_t)p * Bb + b) * Dd + d];
    red[d] = o;
    __syncthreads();
    for (int off = 256; off > 0; off >>= 1) {
        if (d < off) red[d] += red[d + off];
        __syncthreads();
    }
    float mu = red[0] / (float)Dd;
    __syncthreads();
    float df = o - mu;
    red[d] = df * df;
    __syncthreads();
    for (int off = 256; off > 0; off >>= 1) {
        if (d < off) red[d] += red[d + off];
        __syncthreads();
    }
    float var = red[0] / (float)Dd;
    out[b * Dd + d] = df / sqrtf(var + LN_EPS) * gamma[d] + beta[d];
}

// ---------------- launch ----------------

extern "C" void kernel_launch(void* const* d_in, const int* in_sizes, int n_in,
                              void* d_out, int out_size, void* d_ws, size_t ws_size,
                              hipStream_t stream) {
    const float* x         = (const float*)d_in[0];
    const int*   ei        = (const int*)d_in[1];
    const int*   batch     = (const int*)d_in[2];
    const float* W0        = (const float*)d_in[3];
    const float* W_rest    = (const float*)d_in[4];
    const float* att_src   = (const float*)d_in[5];
    const float* att_dst   = (const float*)d_in[6];
    const float* conv_bias = (const float*)d_in[7];
    const float* proj_W    = (const float*)d_in[8];
    const float* proj_b    = (const float*)d_in[9];
    const float* ln_gamma  = (const float*)d_in[10];
    const float* ln_beta   = (const float*)d_in[11];
    float* out = (float*)d_out;

    char* ws = (char*)d_ws;
    size_t off = 0;
    auto alloc = [&](size_t bytes) {
        void* p = ws + off;
        off = (off + bytes + 255) & ~(size_t)255;
        return p;
    };
    unsigned char* h8 = (unsigned char*)alloc((size_t)Nn * HC);   // GEMM out (fp8, agg payload)
    __bf16* h2b     = (__bf16*)alloc((size_t)Nn * HC * 2);        // layer out (bf16)
    __bf16* xb      = (__bf16*)alloc((size_t)Nn * Dd * 2);
    __bf16* W0T     = (__bf16*)alloc((size_t)HC * Dd * 2);
    __bf16* WrT     = (__bf16*)alloc((size_t)3 * HC * HC * 2);
    float*  aprt_s  = (float*)alloc((size_t)4 * Nn * Hh * 4);     // alpha partials
    float*  aprt_d  = (float*)alloc((size_t)4 * Nn * Hh * 4);
    float*  asrc    = (float*)alloc((size_t)Nn * Hh * 4);
    float*  adst    = (float*)alloc((size_t)Nn * Hh * 4);
    float*  ewT     = (float*)alloc((size_t)Hh * ETOT * 4);       // head-major
    float*  dinv    = (float*)alloc((size_t)Nn * Hh * 4);
    int*    deg     = (int*)alloc((size_t)Nn * 4);
    int*    tmp     = (int*)alloc((size_t)Nn * 4);
    int*    bsum    = (int*)alloc((size_t)256 * 4);
    int*    row_ptr = (int*)alloc((size_t)(Nn + 1) * 4);
    int*    cursor  = (int*)alloc((size_t)Nn * 4);
    int*    csr_src = (int*)alloc((size_t)ETOT * 4);
    float*  pooledP = (float*)alloc((size_t)8 * Bb * HC * 4);
    float*  projP   = (float*)alloc((size_t)8 * Bb * Dd * 4);
    (void)ws_size; (void)in_sizes; (void)n_in; (void)out_size;

    // ---- build CSR by destination ----
    hipMemsetAsync(deg, 0, (size_t)Nn * 4, stream);
    count_deg_kernel<<<(ETOT + 255) / 256, 256, 0, stream>>>(ei, deg);
    scan1_kernel<<<NBLK, 256, 0, stream>>>(deg, tmp, bsum);
    scan2_kernel<<<1, 256, 0, stream>>>(bsum);
    scan3_kernel<<<NBLK, 256, 0, stream>>>(tmp, bsum, deg, row_ptr, cursor);
    scatter_kernel<<<(ETOT + 255) / 256, 256, 0, stream>>>(ei, cursor, csr_src);

    // ---- bf16 casts / weight transposes ----
    cast_kernel<<<(Nn * Dd / 4 + 255) / 256, 256, 0, stream>>>(x, xb, Nn * Dd / 4);
    transpose_cast_kernel<<<dim3(HC / 32, Dd / 32, 1), dim3(32, 8), 0, stream>>>(W0, W0T, Dd, HC);
    transpose_cast_kernel<<<dim3(HC / 32, HC / 32, 3), dim3(32, 8), 0, stream>>>(W_rest, WrT, HC, HC);

    // ---- GAT layers ----
    dim3 gemm_grid(8, 160);   // 1280 swizzled ids -> (157 row-blocks, 8 col-blocks)
    for (int l = 0; l < Ll; ++l) {
        const __bf16* Afeat = (l == 0) ? xb : h2b;
        int K = (l == 0) ? Dd : HC;
        const __bf16* BT = (l == 0) ? W0T : (WrT + (size_t)(l - 1) * HC * HC);
        mfma_gemm_kernel<<<gemm_grid, 256, 0, stream>>>(
            Afeat, BT, h8, att_src + l * HC, att_dst + l * HC, aprt_s, aprt_d, Nn, K);
        alpha_sum_kernel<<<NBLK, 256, 0, stream>>>(aprt_s, aprt_d, asrc, adst);
        ew_kernel<<<(Nn + 3) / 4, 256, 0, stream>>>(asrc, adst, row_ptr, csr_src, ewT, dinv);
        agg_slice_kernel<<<dim3(8, Nn / 16), 256, 0, stream>>>(
            h8, ewT, dinv, row_ptr, csr_src, conv_bias + l * HC, h2b);
    }

    // ---- pool + proj + layernorm (all race-free partials, no memsets) ----
    pool_kernel<<<dim3(Bb, 8), 256, 0, stream>>>(h2b, batch, pooledP);
    proj_partial_kernel<<<dim3(Bb, 8), 512, 0, stream>>>(pooledP, batch, proj_W, projP);
    ln_kernel<<<Bb, 512, 0, stream>>>(projP, proj_b, ln_gamma, ln_beta, out);
}